// Round 6
// baseline (1255.694 us; speedup 1.0000x reference)
//
#include <hip/hip_runtime.h>
#include <math.h>
#include <cstdint>

#define B_   64
#define N_   2048
#define E_   32768
#define FIN  256
#define H_   512

typedef __bf16 bf16x8 __attribute__((ext_vector_type(8)));
typedef float  f32x4  __attribute__((ext_vector_type(4)));

__device__ __forceinline__ unsigned short f2bf(float f) {
  unsigned u = __float_as_uint(f);
  u += 0x7FFF + ((u >> 16) & 1);            // RNE
  return (unsigned short)(u >> 16);
}
__device__ __forceinline__ unsigned pk2(float a, float b) {
#if defined(__gfx950__)
  unsigned r;
  asm("v_cvt_pk_bf16_f32 %0, %1, %2" : "=v"(r) : "v"(a), "v"(b));
  return r;
#else
  return (unsigned)f2bf(a) | ((unsigned)f2bf(b) << 16);
#endif
}
__device__ __forceinline__ float bflo(unsigned u) { return __uint_as_float(u << 16); }
__device__ __forceinline__ float bfhi(unsigned u) { return __uint_as_float(u & 0xFFFF0000u); }

__device__ __forceinline__ void accum8(float* acc, uint4 u, float c) {
  acc[0] += c * bflo(u.x); acc[1] += c * bfhi(u.x);
  acc[2] += c * bflo(u.y); acc[3] += c * bfhi(u.y);
  acc[4] += c * bflo(u.z); acc[5] += c * bfhi(u.z);
  acc[6] += c * bflo(u.w); acc[7] += c * bfhi(u.w);
}

// async global->LDS, 16B per lane; LDS dest = wave-uniform base + lane*16
__device__ __forceinline__ void glds16(const void* g, void* l) {
  __builtin_amdgcn_global_load_lds(
      (const __attribute__((address_space(1))) unsigned int*)g,
      (__attribute__((address_space(3))) unsigned int*)l, 16, 0, 0);
}

// ---------------- x fp32 -> bf16 ----------------
__global__ void xcvt_k(const float* __restrict__ x, unsigned short* __restrict__ xb) {
  int i = blockIdx.x * 256 + threadIdx.x;   // chunks of 4 floats
  float4 f = reinterpret_cast<const float4*>(x)[i];
  uint2 o; o.x = pk2(f.x, f.y); o.y = pk2(f.z, f.w);
  reinterpret_cast<uint2*>(xb)[i] = o;
}

// ---------------- weight transpose+cast: Wt[n][k] bf16 from W[k][n] fp32 (Nn==512) ----------
__global__ void wcvt_k(const float* __restrict__ W, unsigned short* __restrict__ Wt, int K) {
  int idx = blockIdx.x * 256 + threadIdx.x;     // < K*512
  int k = idx >> 9, n = idx & 511;
  Wt[n * K + k] = f2bf(W[idx]);
}

// ---------------- MFMA GEMM: Y[M,512](bf16) = X[M,K] @ Wt^T, 128x256 tile ----------------
// 4 waves, each computes 64x128 (MFMA:LDS-read balanced). 1D grid XCD-grouped:
// bid = xcd + 8*(colb + 2*strip_in_xcd). LDS XOR-swizzled per 256-chunk region
// (chunk c at c^((c>>3)&7)); staging derives the per-lane global source from the
// swizzled position so glds16's lane-contiguous deposit lands correctly.
// Epilogue: DPP shuffle-pack (xor1, xor2) -> fully-coalesced uint2 stores
// (128B per 16-lane phase). Optional bias+relu, row scale tanhv, fused scorer hs.
__global__ __launch_bounds__(256) void gemm_mfma(
    const unsigned short* __restrict__ Xb,
    const int* __restrict__ perm, const float* __restrict__ tanhv,
    const unsigned short* __restrict__ Wt, unsigned short* __restrict__ Y,
    int K, int kl2, int nsl2,
    const float* __restrict__ bias, const float* __restrict__ wp, float* __restrict__ hs) {
  __shared__ uint4 As[512];    // 128 rows x BK32 : 2 regions of 256 chunks
  __shared__ uint4 Bs[1024];   // 256 cols x BK32 : 4 regions of 256 chunks
  const int tid = threadIdx.x;
  const int w = tid >> 6, L = tid & 63;
  const int bid = blockIdx.x;
  const int xcd = bid & 7;
  const int t = bid >> 3;
  const int colb = t & 1;
  const int strip = ((t >> 1) << 3) + xcd;
  const int m0 = strip * 128;
  const int e = L & 15, q = L >> 4;
  const int mh = w & 1, nh = w >> 1;

  // staging: LDS position (region*256 + w*64 + L) holds logical chunk (w*64+L)^sw3
  const int sw3 = (L >> 3) & 7;
  const int cA = (w * 64 + L) ^ sw3;
  const int rloc = cA >> 2;           // row/col within 64-wide region
  const int kcs = (cA & 3) * 8;       // bf16 offset within BK=32 slab

  f32x4 acc[4][8];
#pragma unroll
  for (int j = 0; j < 4; j++)
#pragma unroll
    for (int nn = 0; nn < 8; nn++) acc[j][nn] = (f32x4){0.f, 0.f, 0.f, 0.f};

  size_t asrc[2];
#pragma unroll
  for (int i = 0; i < 2; i++) {
    int g = m0 + i * 64 + rloc;
    size_t row;
    if (perm) {
      int b = g >> kl2;
      int node = perm[g];
      row = (size_t)(b << nsl2) + node;
    } else {
      row = (size_t)g;
    }
    asrc[i] = row * (size_t)K + kcs;
  }
  size_t bsrc[4];
#pragma unroll
  for (int i = 0; i < 4; i++) bsrc[i] = (size_t)(colb * 256 + i * 64 + rloc) * K + kcs;

  const int fo = e * 4 + q;
  const int fosw = fo ^ (fo >> 3);

  for (int k0 = 0; k0 < K; k0 += 32) {
    glds16(Xb + asrc[0] + k0, &As[0 * 256 + w * 64]);
    glds16(Xb + asrc[1] + k0, &As[1 * 256 + w * 64]);
    glds16(Wt + bsrc[0] + k0, &Bs[0 * 256 + w * 64]);
    glds16(Wt + bsrc[1] + k0, &Bs[1 * 256 + w * 64]);
    glds16(Wt + bsrc[2] + k0, &Bs[2 * 256 + w * 64]);
    glds16(Wt + bsrc[3] + k0, &Bs[3 * 256 + w * 64]);
    __syncthreads();
    bf16x8 af[4], bfr[8];
#pragma unroll
    for (int j = 0; j < 4; j++)
      af[j] = __builtin_bit_cast(bf16x8, As[mh * 256 + j * 64 + fosw]);
#pragma unroll
    for (int nn = 0; nn < 8; nn++)
      bfr[nn] = __builtin_bit_cast(bf16x8, Bs[(nh * 2 + (nn >> 2)) * 256 + (nn & 3) * 64 + fosw]);
#pragma unroll
    for (int j = 0; j < 4; j++)
#pragma unroll
      for (int nn = 0; nn < 8; nn++)
        acc[j][nn] = __builtin_amdgcn_mfma_f32_16x16x32_bf16(af[j], bfr[nn], acc[j][nn], 0, 0, 0);
    __syncthreads();
  }
  // epilogue
  const int colbase = colb * 256 + nh * 128;
  float bs[8], wsv[8];
#pragma unroll
  for (int nn = 0; nn < 8; nn++) {
    int coly = colbase + nn * 16 + e;
    bs[nn]  = bias ? bias[coly] : 0.f;
    wsv[nn] = wp ? wp[coly] : 0.f;
  }
#pragma unroll
  for (int j = 0; j < 4; j++) {
#pragma unroll
    for (int r = 0; r < 4; r++) {
      int grow = m0 + (mh * 4 + j) * 16 + q * 4 + r;
      float t2 = tanhv ? tanhv[grow] : 1.0f;
      float v[8];
#pragma unroll
      for (int nn = 0; nn < 8; nn++) {
        float val = acc[j][nn][r] * t2;
        if (bias) val = fmaxf(val + bs[nn], 0.f);
        v[nn] = val;
      }
      // level-1 pack (DPP xor-1): u[t] = 2 cols of tile 2t+(e&1)
      unsigned u[4];
      const bool odd = (e & 1);
#pragma unroll
      for (int tt = 0; tt < 4; tt++) {
        float a = v[2 * tt], b = v[2 * tt + 1];
        float a2 = __shfl_xor(a, 1, 64);
        float b2 = __shfl_xor(b, 1, 64);
        u[tt] = odd ? pk2(b2, b) : pk2(a, a2);
      }
      // level-2 pack (DPP xor-2) -> uint2, fully coalesced per 16-lane phase
      unsigned short* Yr = Y + (size_t)grow * 512;
#pragma unroll
      for (int s = 0; s < 2; s++) {
        unsigned ua = u[2 * s], ub = u[2 * s + 1];
        unsigned ua2 = __shfl_xor(ua, 2, 64);
        unsigned ub2 = __shfl_xor(ub, 2, 64);
        uint2 wv;
        if (e & 2) { wv.x = ub2; wv.y = ub; }
        else       { wv.x = ua;  wv.y = ua2; }
        int T = s * 4 + (e & 3);
        *(uint2*)(Yr + colbase + T * 16 + (e & 12)) = wv;
      }
      if (wp) {
        float p = 0.f;
#pragma unroll
        for (int nn = 0; nn < 8; nn++) p += v[nn] * wsv[nn];
        p += __shfl_xor(p, 1, 64); p += __shfl_xor(p, 2, 64);
        p += __shfl_xor(p, 4, 64); p += __shfl_xor(p, 8, 64);
        if ((L & 15) == 0) atomicAdd(&hs[grow], p);
      }
    }
  }
}

// ---------------- CSR build (dst<0 == masked edge) ----------------
__global__ void count_k(const int* __restrict__ dst, int* __restrict__ cnt, int nl2) {
  int g = blockIdx.x * 256 + threadIdx.x;
  int d = dst[g];
  if (d < 0) return;
  int b = g >> 15;
  atomicAdd(&cnt[(b << nl2) + d], 1);
}

__global__ __launch_bounds__(256) void scan_k(const int* __restrict__ cnt,
                                              int* __restrict__ rowptr, int* __restrict__ cursor,
                                              float* __restrict__ deg, float* __restrict__ dinv, int n) {
  int b = blockIdx.x, tid = threadIdx.x;
  __shared__ int ls[2048];
  __shared__ int ch[256];
  int per = n >> 8;
  int base = tid * per;
  int s = 0;
  for (int i = 0; i < per; i++) { int v = cnt[b * n + base + i]; ls[base + i] = v; s += v; }
  ch[tid] = s;
  __syncthreads();
  for (int off = 1; off < 256; off <<= 1) {
    int v = (tid >= off) ? ch[tid - off] : 0;
    __syncthreads();
    ch[tid] += v;
    __syncthreads();
  }
  int run = (tid == 0) ? 0 : ch[tid - 1];
  for (int i = 0; i < per; i++) {
    int v = ls[base + i];
    rowptr[b * (n + 1) + base + i] = run;
    cursor[b * n + base + i] = run;
    float d = (float)(v + 1);
    deg[b * n + base + i] = d;
    dinv[b * n + base + i] = 1.0f / sqrtf(d);
    run += v;
  }
  if (tid == 255) rowptr[b * (n + 1) + n] = run;
}

__global__ void fill_k(const int* __restrict__ src, const int* __restrict__ dst,
                       const float* __restrict__ dinv, int* cursor, int* col,
                       float* ce, int nl2) {
  int g = blockIdx.x * 256 + threadIdx.x;
  int d = dst[g];
  if (d < 0) return;
  int b = g >> 15;
  int s = src[g];
  int pos = atomicAdd(&cursor[(b << nl2) + d], 1);
  col[(b << 15) + pos] = s;
  ce[(b << 15) + pos] = dinv[(b << nl2) + s] * dinv[(b << nl2) + d];
}

// ---------------- layer-1 aggregation over x (256-wide): Xa = Ahat x  ----------------
__global__ __launch_bounds__(256) void aggx_k(
    const unsigned short* __restrict__ X,
    const int* __restrict__ rowptr, const int* __restrict__ col,
    const float* __restrict__ ce, const float* __restrict__ deg,
    unsigned short* __restrict__ Xa) {
  const int w = threadIdx.x >> 6, L = threadIdx.x & 63;
  const int xcd = blockIdx.x & 7;
  const int slot = blockIdx.x >> 3;
  const int gslot = slot >> 9;           // 512 wave-slots per graph
  const int v4 = slot & 511;
  const int b = (gslot << 3) + xcd;
  const int v = v4 * 4 + w;
  const int bbase = b << 11;
  const int vg = bbase + v;
  const int rb = b * (N_ + 1) + v;
  const int st = rowptr[rb], en = rowptr[rb + 1];
  const int* cb = col + (b << 15);
  const float* cee = ce + (b << 15);
  const int h = L >> 5, hl = L & 31;
  const unsigned short* Xb_ = X + (size_t)bbase * 256 + hl * 8;
  const int T = en - st + 1;             // edges + self
  const float selfc = 1.0f / deg[vg];
  float acc[8] = {0.f, 0.f, 0.f, 0.f, 0.f, 0.f, 0.f, 0.f};
  for (int t = h; t < T; t += 2) {
    bool isE = (t < T - 1);
    int s = isE ? cb[st + t] : v;
    float c = isE ? cee[st + t] : selfc;
    uint4 u = *(const uint4*)(Xb_ + (size_t)s * 256);
    accum8(acc, u, c);
  }
#pragma unroll
  for (int i = 0; i < 8; i++) acc[i] += __shfl_xor(acc[i], 32, 64);
  if (h == 0) {
    uint4 o;
    o.x = pk2(acc[0], acc[1]); o.y = pk2(acc[2], acc[3]);
    o.z = pk2(acc[4], acc[5]); o.w = pk2(acc[6], acc[7]);
    *(uint4*)(Xa + (size_t)vg * 256 + hl * 8) = o;
  }
}

// ---------------- GCN aggregate (512-wide) + relu + fused scorer matvec ----------------
template <int NL2>
__global__ __launch_bounds__(256) void agg_k(
    const unsigned short* __restrict__ H,
    const int* __restrict__ rowptr, const int* __restrict__ col,
    const float* __restrict__ ce, const float* __restrict__ deg,
    const float* __restrict__ bias, const float* __restrict__ wp,
    unsigned short* __restrict__ C, float* __restrict__ hs) {
  const int n = 1 << NL2;
  const int xcd = blockIdx.x & 7;
  const int slot = blockIdx.x >> 3;
  const int gslot = slot >> (NL2 - 2);
  const int v4 = slot & ((1 << (NL2 - 2)) - 1);
  const int b = (gslot << 3) + xcd;
  const int w = threadIdx.x >> 6, L = threadIdx.x & 63;
  const int v = v4 * 4 + w;
  const int bbase = b << NL2;
  const int vg = bbase + v;
  const int rb = b * (n + 1) + v;
  const int st = rowptr[rb], en = rowptr[rb + 1];
  const int* cb = col + (b << 15);
  const float* cee = ce + (b << 15);
  const unsigned short* Hb_ = H + (size_t)bbase * 512 + (size_t)L * 8;

  float acc[8] = {0.f, 0.f, 0.f, 0.f, 0.f, 0.f, 0.f, 0.f};
  int e2 = st;
  for (; e2 + 4 <= en; e2 += 4) {
    int s0 = cb[e2], s1 = cb[e2 + 1], s2 = cb[e2 + 2], s3 = cb[e2 + 3];
    float c0 = cee[e2], c1 = cee[e2 + 1], c2 = cee[e2 + 2], c3 = cee[e2 + 3];
    uint4 u0 = *(const uint4*)(Hb_ + (size_t)s0 * 512);
    uint4 u1 = *(const uint4*)(Hb_ + (size_t)s1 * 512);
    uint4 u2 = *(const uint4*)(Hb_ + (size_t)s2 * 512);
    uint4 u3 = *(const uint4*)(Hb_ + (size_t)s3 * 512);
    accum8(acc, u0, c0); accum8(acc, u1, c1);
    accum8(acc, u2, c2); accum8(acc, u3, c3);
  }
  for (; e2 < en; e2++) {
    int s = cb[e2];
    uint4 u = *(const uint4*)(Hb_ + (size_t)s * 512);
    accum8(acc, u, cee[e2]);
  }
  {
    float idg = 1.0f / deg[vg];
    uint4 u = *(const uint4*)(Hb_ + (size_t)v * 512);
    accum8(acc, u, idg);
  }
  float4 bLo = *(const float4*)(bias + L * 8);
  float4 bHi = *(const float4*)(bias + L * 8 + 4);
  acc[0] = fmaxf(acc[0] + bLo.x, 0.f); acc[1] = fmaxf(acc[1] + bLo.y, 0.f);
  acc[2] = fmaxf(acc[2] + bLo.z, 0.f); acc[3] = fmaxf(acc[3] + bLo.w, 0.f);
  acc[4] = fmaxf(acc[4] + bHi.x, 0.f); acc[5] = fmaxf(acc[5] + bHi.y, 0.f);
  acc[6] = fmaxf(acc[6] + bHi.z, 0.f); acc[7] = fmaxf(acc[7] + bHi.w, 0.f);
  uint4 o;
  o.x = pk2(acc[0], acc[1]); o.y = pk2(acc[2], acc[3]);
  o.z = pk2(acc[4], acc[5]); o.w = pk2(acc[6], acc[7]);
  *(uint4*)(C + (size_t)vg * 512 + L * 8) = o;
  float4 wLo = *(const float4*)(wp + L * 8);
  float4 wHi = *(const float4*)(wp + L * 8 + 4);
  float p = acc[0] * wLo.x + acc[1] * wLo.y + acc[2] * wLo.z + acc[3] * wLo.w
          + acc[4] * wHi.x + acc[5] * wHi.y + acc[6] * wHi.z + acc[7] * wHi.w;
#pragma unroll
  for (int off = 32; off > 0; off >>= 1) p += __shfl_down(p, off, 64);
  if (L == 0) hs[vg] = p;
}

__global__ void scoreagg_k(const float* __restrict__ hs, const int* __restrict__ rowptr,
                           const int* __restrict__ col, const float* __restrict__ ce,
                           const float* __restrict__ deg, const float* __restrict__ bp,
                           float* __restrict__ score, int nl2) {
  int idx = blockIdx.x * 256 + threadIdx.x;
  int n = 1 << nl2;
  int b = idx >> nl2, v = idx & (n - 1);
  int rb = b * (n + 1) + v;
  int st = rowptr[rb], en = rowptr[rb + 1];
  const int* cb = col + (b << 15);
  const float* cee = ce + (b << 15);
  int bbase = b << nl2;
  float acc = 0.f;
  int e = st;
  for (; e + 4 <= en; e += 4) {
    acc += hs[bbase + cb[e]] * cee[e] + hs[bbase + cb[e + 1]] * cee[e + 1]
         + hs[bbase + cb[e + 2]] * cee[e + 2] + hs[bbase + cb[e + 3]] * cee[e + 3];
  }
  for (; e < en; e++) acc += hs[bbase + cb[e]] * cee[e];
  score[idx] = acc + hs[idx] / deg[idx] + bp[0];
}

// ---------------- per-batch bitonic top-k (desc score, tie: lower index) ----------------
__global__ __launch_bounds__(1024) void topk_k(const float* __restrict__ score, int* __restrict__ perm,
                                               float* __restrict__ tanhv, int* __restrict__ newidx,
                                               int n, int k) {
  int b = blockIdx.x, tid = threadIdx.x;
  __shared__ float ss[2048];
  __shared__ int si[2048];
  for (int i = tid; i < n; i += 1024) { ss[i] = score[b * n + i]; si[i] = i; }
  __syncthreads();
  for (int size = 2; size <= n; size <<= 1) {
    for (int stride = size >> 1; stride > 0; stride >>= 1) {
      for (int i = tid; i < n; i += 1024) {
        int j = i ^ stride;
        if (j > i) {
          bool up = ((i & size) == 0);
          float fi = ss[i], fj = ss[j];
          int ii = si[i], ij = si[j];
          bool iBefore = (fi > fj) || (fi == fj && ii < ij);
          bool sw = up ? (!iBefore) : iBefore;
          if (sw) { ss[i] = fj; ss[j] = fi; si[i] = ij; si[j] = ii; }
        }
      }
      __syncthreads();
    }
  }
  for (int r = tid; r < n; r += 1024) newidx[b * n + si[r]] = (r < k) ? r : -1;
  for (int r = tid; r < k; r += 1024) { perm[b * k + r] = si[r]; tanhv[b * k + r] = tanhf(ss[r]); }
}

// ---------------- fused edge reindex + degree count (in-place safe) ----------------
__global__ void reindex_count_k(const int* srcO, const int* dstO, const int* newidx,
                                int* srcN, int* dstN, int* cnt, int nl2new) {
  int g = blockIdx.x * 256 + threadIdx.x;
  int b = g >> 15;
  int dd = dstO[g];
  int sN = 0, dN = -1;
  if (dd >= 0) {
    int ns = newidx[(b << (nl2new + 1)) + srcO[g]];
    int nd = newidx[(b << (nl2new + 1)) + dd];
    if (ns >= 0 && nd >= 0) {
      sN = ns; dN = nd;
      atomicAdd(&cnt[(b << nl2new) + nd], 1);
    }
  }
  srcN[g] = sN; dstN[g] = dN;
}

// ---------------- readout stats via gather+scale: partial then reduce ----------------
__global__ __launch_bounds__(512) void statsp_k(const unsigned short* __restrict__ C,
    const int* __restrict__ perm, const float* __restrict__ tv,
    float* __restrict__ zp, int nsl2, int k, int kch) {
  int b = blockIdx.x, rg = blockIdx.y, f = threadIdx.x;
  int r0 = rg * kch;
  float mx = -1e30f, sm = 0.f;
#pragma unroll 4
  for (int r = r0; r < r0 + kch; r++) {
    int node = perm[b * k + r];
    float t = tv[b * k + r];
    float val = __uint_as_float((unsigned)C[((size_t)((b << nsl2) + node)) * 512 + f] << 16) * t;
    mx = fmaxf(mx, val); sm += val;
  }
  zp[(size_t)(b * 8 + rg) * 1024 + f] = mx;
  zp[(size_t)(b * 8 + rg) * 1024 + 512 + f] = sm;
}

__global__ __launch_bounds__(512) void statsr_k(const float* __restrict__ zp,
                                                float* __restrict__ z, int k) {
  int b = blockIdx.x, f = threadIdx.x;
  float mx = -1e30f, sm = 0.f;
#pragma unroll
  for (int g = 0; g < 8; g++) {
    mx = fmaxf(mx, zp[(size_t)(b * 8 + g) * 1024 + f]);
    sm += zp[(size_t)(b * 8 + g) * 1024 + 512 + f];
  }
  z[b * 1024 + f] += mx;
  z[b * 1024 + 512 + f] += sm / (float)k;
}

// ---------------- fused MLP head ----------------
__global__ __launch_bounds__(256) void mlp_k(const float* __restrict__ z, const float* __restrict__ W1,
                                             const float* __restrict__ b1, const float* __restrict__ W2,
                                             const float* __restrict__ b2, const float* __restrict__ piW,
                                             const float* __restrict__ pib, const float* __restrict__ vW,
                                             const float* __restrict__ vb, float* __restrict__ out) {
  int b = blockIdx.x, tid = threadIdx.x;
  __shared__ float zr[1024];
  __shared__ float z1[512];
  __shared__ float z2[256];
  __shared__ float pl[128];
  __shared__ float red[2];
  for (int i = tid; i < 1024; i += 256) zr[i] = z[b * 1024 + i];
  __syncthreads();
  for (int o = tid; o < 512; o += 256) {
    float a = b1[o];
    for (int i = 0; i < 1024; i++) a += zr[i] * W1[i * 512 + o];
    z1[o] = fmaxf(a, 0.f);
  }
  __syncthreads();
  {
    int o = tid;
    float a = b2[o];
    for (int i = 0; i < 512; i++) a += z1[i] * W2[i * 256 + o];
    z2[o] = fmaxf(a, 0.f);
  }
  __syncthreads();
  if (tid < 128) {
    float a = pib[tid];
    for (int i = 0; i < 256; i++) a += z2[i] * piW[i * 128 + tid];
    pl[tid] = a;
  }
  __syncthreads();
  if (tid == 0) {
    float m = -1e30f;
    for (int i = 0; i < 128; i++) m = fmaxf(m, pl[i]);
    float se = 0.f;
    for (int i = 0; i < 128; i++) se += expf(pl[i] - m);
    red[0] = m; red[1] = logf(se);
    float a = vb[0];
    for (int i = 0; i < 256; i++) a += z2[i] * vW[i];
    out[B_ * 128 + b] = fmaxf(a, 0.f);
  }
  __syncthreads();
  if (tid < 128) out[b * 128 + tid] = pl[tid] - red[0] - red[1];
}

extern "C" void kernel_launch(void* const* d_in, const int* in_sizes, int n_in,
                              void* d_out, int out_size, void* d_ws, size_t ws_size,
                              hipStream_t stream) {
  const float* x    = (const float*)d_in[0];
  const int*   src0 = (const int*)d_in[1];
  const int*   dst0 = (const int*)d_in[2];
  const float* W1   = (const float*)d_in[3];
  const float* b1   = (const float*)d_in[4];
  const float* Wp1  = (const float*)d_in[5];
  const float* bp1  = (const float*)d_in[6];
  const float* W2   = (const float*)d_in[7];
  const float* b2   = (const float*)d_in[8];
  const float* Wp2  = (const float*)d_in[9];
  const float* bp2  = (const float*)d_in[10];
  const float* W3   = (const float*)d_in[11];
  const float* b3   = (const float*)d_in[12];
  const float* Wp3  = (const float*)d_in[13];
  const float* bp3  = (const float*)d_in[14];
  const float* l1W  = (const float*)d_in[15];
  const float* l1b  = (const float*)d_in[16];
  const float* l2W  = (const float*)d_in[17];
  const float* l2b  = (const float*)d_in[18];
  const float* piW  = (const float*)d_in[19];
  const float* pib  = (const float*)d_in[20];
  const float* vW   = (const float*)d_in[21];
  const float* vb   = (const float*)d_in[22];
  float* out = (float*)d_out;
  (void)in_sizes; (void)n_in; (void)out_size; (void)ws_size;

  // C lives in d_in[0]'s buffer (128 MB): x is dead after xcvt_k; harness restores
  // inputs before every launch.
  unsigned short* Cb = (unsigned short*)d_in[0];

  char* base = (char*)d_ws;
  size_t off = 0;
  auto alloc = [&](size_t bytes) -> void* {
    void* r = base + off;
    off += (bytes + 255) & ~(size_t)255;
    return r;
  };
  // Total ~230 MB (proven budget: 235 MB OK in round 2)
  unsigned short* Hb   = (unsigned short*)alloc((size_t)B_ * 1024 * H_ * 2);     // 64 MB
  unsigned short* xb   = (unsigned short*)alloc((size_t)B_ * N_ * FIN * 2);      // 64 MB
  unsigned short* Xa   = (unsigned short*)alloc((size_t)B_ * N_ * FIN * 2);      // 64 MB
  unsigned short* W1t  = (unsigned short*)alloc((size_t)512 * 256 * 2);
  unsigned short* W2t  = (unsigned short*)alloc((size_t)512 * 512 * 2);
  unsigned short* W3t  = (unsigned short*)alloc((size_t)512 * 512 * 2);
  int*   srcA   = (int*)alloc((size_t)B_ * E_ * 4);                              // 8 MB
  int*   dstA   = (int*)alloc((size_t)B_ * E_ * 4);                              // 8 MB
  int*   col    = (int*)alloc((size_t)B_ * E_ * 4);                              // 8 MB
  float* coefE  = (float*)alloc((size_t)B_ * E_ * 4);                            // 8 MB
  int*   cnt    = (int*)alloc((size_t)B_ * N_ * 4);
  int*   cursor = (int*)alloc((size_t)B_ * N_ * 4);
  int*   rowptr = (int*)alloc((size_t)B_ * (N_ + 1) * 4);
  float* deg    = (float*)alloc((size_t)B_ * N_ * 4);
  float* dinv   = (float*)alloc((size_t)B_ * N_ * 4);
  float* hs     = (float*)alloc((size_t)B_ * N_ * 4);
  float* score  = (float*)alloc((size_t)B_ * N_ * 4);
  int*   newidx = (int*)alloc((size_t)B_ * N_ * 4);
  int*   perm   = (int*)alloc((size_t)B_ * 1024 * 4);
  float* tanhv  = (float*)alloc((size_t)B_ * 1024 * 4);
  float* zpart  = (float*)alloc((size_t)B_ * 8 * 1024 * 4);
  float* z      = (float*)alloc((size_t)B_ * 1024 * 4);

  const int EB = B_ * E_ / 256;   // 8192

  xcvt_k<<<B_ * N_ * FIN / 4 / 256, 256, 0, stream>>>(x, xb);
  wcvt_k<<<256 * 512 / 256, 256, 0, stream>>>(W1, W1t, 256);
  wcvt_k<<<512 * 512 / 256, 256, 0, stream>>>(W2, W2t, 512);
  wcvt_k<<<512 * 512 / 256, 256, 0, stream>>>(W3, W3t, 512);
  hipMemsetAsync(z, 0, (size_t)B_ * 1024 * 4, stream);

  // ========== layer 1: n=2048 (nl2=11), k=1024 ==========
  {
    hipMemsetAsync(cnt, 0, (size_t)B_ * 2048 * 4, stream);
    count_k<<<EB, 256, 0, stream>>>(dst0, cnt, 11);
    scan_k<<<B_, 256, 0, stream>>>(cnt, rowptr, cursor, deg, dinv, 2048);
    fill_k<<<EB, 256, 0, stream>>>(src0, dst0, dinv, cursor, col, coefE, 11);
    aggx_k<<<B_ * 2048 / 4, 256, 0, stream>>>(xb, rowptr, col, coefE, deg, Xa);
    hipMemsetAsync(hs, 0, (size_t)B_ * 2048 * 4, stream);
    gemm_mfma<<<B_ * 2048 / 128 * 2, 256, 0, stream>>>(
        Xa, nullptr, nullptr, W1t, Cb, 256, 0, 0, b1, Wp1, hs);
    scoreagg_k<<<B_ * 2048 / 256, 256, 0, stream>>>(hs, rowptr, col, coefE, deg, bp1, score, 11);
    topk_k<<<B_, 1024, 0, stream>>>(score, perm, tanhv, newidx, 2048, 1024);
    statsp_k<<<dim3(B_, 8), 512, 0, stream>>>(Cb, perm, tanhv, zpart, 11, 1024, 128);
    statsr_k<<<B_, 512, 0, stream>>>(zpart, z, 1024);
    hipMemsetAsync(cnt, 0, (size_t)B_ * 1024 * 4, stream);
    reindex_count_k<<<EB, 256, 0, stream>>>(src0, dst0, newidx, srcA, dstA, cnt, 10);
    scan_k<<<B_, 256, 0, stream>>>(cnt, rowptr, cursor, deg, dinv, 1024);
    fill_k<<<EB, 256, 0, stream>>>(srcA, dstA, dinv, cursor, col, coefE, 10);
  }
  // ========== layer 2: n=1024 (nl2=10), gather from 2048 (nsl2=11), k=512 ==========
  {
    gemm_mfma<<<B_ * 1024 / 128 * 2, 256, 0, stream>>>(
        Cb, perm, tanhv, W2t, Hb, 512, 10, 11, nullptr, nullptr, nullptr);
    agg_k<10><<<B_ * 1024 / 4, 256, 0, stream>>>(Hb, rowptr, col, coefE, deg, b2, Wp2, Cb, hs);
    scoreagg_k<<<B_ * 1024 / 256, 256, 0, stream>>>(hs, rowptr, col, coefE, deg, bp2, score, 10);
    topk_k<<<B_, 1024, 0, stream>>>(score, perm, tanhv, newidx, 1024, 512);
    statsp_k<<<dim3(B_, 8), 512, 0, stream>>>(Cb, perm, tanhv, zpart, 10, 512, 64);
    statsr_k<<<B_, 512, 0, stream>>>(zpart, z, 512);
    hipMemsetAsync(cnt, 0, (size_t)B_ * 512 * 4, stream);
    reindex_count_k<<<EB, 256, 0, stream>>>(srcA, dstA, newidx, srcA, dstA, cnt, 9);
    scan_k<<<B_, 256, 0, stream>>>(cnt, rowptr, cursor, deg, dinv, 512);
    fill_k<<<EB, 256, 0, stream>>>(srcA, dstA, dinv, cursor, col, coefE, 9);
  }
  // ========== layer 3: n=512 (nl2=9), gather from 1024 (nsl2=10), k=256 ==========
  {
    gemm_mfma<<<B_ * 512 / 128 * 2, 256, 0, stream>>>(
        Cb, perm, tanhv, W3t, Hb, 512, 9, 10, nullptr, nullptr, nullptr);
    agg_k<9><<<B_ * 512 / 4, 256, 0, stream>>>(Hb, rowptr, col, coefE, deg, b3, Wp3, Cb, hs);
    scoreagg_k<<<B_ * 512 / 256, 256, 0, stream>>>(hs, rowptr, col, coefE, deg, bp3, score, 9);
    topk_k<<<B_, 1024, 0, stream>>>(score, perm, tanhv, newidx, 512, 256);
    statsp_k<<<dim3(B_, 8), 512, 0, stream>>>(Cb, perm, tanhv, zpart, 9, 256, 32);
    statsr_k<<<B_, 512, 0, stream>>>(zpart, z, 256);
  }

  mlp_k<<<B_, 256, 0, stream>>>(z, l1W, l1b, l2W, l2b, piW, pib, vW, vb, out);
}